// Round 9
// baseline (183.960 us; speedup 1.0000x reference)
//
#include <hip/hip_runtime.h>
#include <hip/hip_fp16.h>

#define NN 50000
#define EE 800000
#define NBUCK 196   // dst buckets of 256 nodes each
#define CAP 5120    // per-bucket edge capacity (mean ~4082, sigma ~64 -> 16 sigma)
#define TILEA 1024
#define NBA ((EE + TILEA - 1) / TILEA)   // 782
#define SRCS_MAX (EE + 8 * NN)           // padded CSR upper bound (1.2M)

typedef _Float16 half8 __attribute__((ext_vector_type(8)));
typedef float floatx4 __attribute__((ext_vector_type(4)));

// ---- Stage A (fused): blocks [0,NBA) bucketA; blocks [NBA,NBA+6) prep ----------
// prep: Bf1[kk(4)][ct(4)][lane(64)][8]: B[n=ct*16+(L&15)][k=kk*32+(L>>4)*8+j]
//       Bf2[kk(2)][ct(3)][lane(64)][8]: cols >= 40 zero-padded; sentinels
__global__ __launch_bounds__(256) void k_A(const int* __restrict__ ei,
        int* __restrict__ cursor, unsigned* __restrict__ bucketData,
        const float* __restrict__ W1, const float* __restrict__ W2,
        _Float16* __restrict__ Bf1, _Float16* __restrict__ Bf2,
        float* __restrict__ alsrc, float* __restrict__ al2s) {
    if (blockIdx.x < NBA) {
        // ---- bucketA: coarse bucket by dst>>8, LDS-staged, coalesced-run writes
        __shared__ int cnt[NBUCK], base[NBUCK];
        int t = threadIdx.x;
        for (int i = t; i < NBUCK; i += 256) cnt[i] = 0;
        __syncthreads();
        int e0 = blockIdx.x * TILEA;
        int nE = min(TILEA, EE - e0);
        unsigned pk[4]; int bk[4], rk[4];
        int m = 0;
        for (int i = t; i < nE; i += 256) {
            int e = e0 + i;
            int s = ei[e], d = ei[EE + e];
            pk[m] = ((unsigned)d << 16) | (unsigned)s;
            bk[m] = d >> 8;
            rk[m] = atomicAdd(&cnt[bk[m]], 1);
            m++;
        }
        __syncthreads();
        for (int i = t; i < NBUCK; i += 256)
            base[i] = (cnt[i] > 0) ? atomicAdd(&cursor[i], cnt[i]) : 0;
        __syncthreads();
        for (int k = 0; k < m; k++) {
            int pos = base[bk[k]] + rk[k];
            if (pos < CAP) bucketData[(size_t)bk[k] * CAP + pos] = pk[k];
        }
        return;
    }
    // ---- prep
    int tid = (blockIdx.x - NBA) * 256 + threadIdx.x;
    if (tid < 1024) {
        int kk = tid >> 8, ct = (tid >> 6) & 3, L = tid & 63;
        int k0 = kk * 32 + (L >> 4) * 8, col = ct * 16 + (L & 15);
        half8 v;
        #pragma unroll
        for (int j = 0; j < 8; j++) v[j] = (_Float16)W1[(k0 + j) * 64 + col];
        *(half8*)(Bf1 + ((size_t)((kk * 4 + ct) * 64 + L)) * 8) = v;
    } else if (tid < 1024 + 384) {
        int u = tid - 1024;
        int kk = u / 192, rem = u % 192;
        int ct = rem >> 6, L = rem & 63;
        int k0 = kk * 32 + (L >> 4) * 8, col = ct * 16 + (L & 15);
        half8 v;
        #pragma unroll
        for (int j = 0; j < 8; j++)
            v[j] = (col < 40) ? (_Float16)W2[(k0 + j) * 40 + col] : (_Float16)0.f;
        *(half8*)(Bf2 + ((size_t)((kk * 3 + ct) * 64 + L)) * 8) = v;
    } else {
        int u = tid - 1408;
        if (u < 8) alsrc[(size_t)NN * 8 + u] = -1e30f;
        if (u == 8) al2s[NN] = -1e30f;
    }
}

// ---- Stage B (fused, 1024 threads): blocks [0,NBUCK) bucketB; rest gemm1 -------
__global__ __launch_bounds__(1024) void k_B(const unsigned* __restrict__ bucketData,
        const int* __restrict__ cursor,
        int2* __restrict__ rowseg, int* __restrict__ srcs,
        const float* __restrict__ x, const float* __restrict__ topo,
        const _Float16* __restrict__ Bf1,
        const float* __restrict__ a_src, const float* __restrict__ a_dst,
        __half* __restrict__ h1, float* __restrict__ alsrc, float* __restrict__ aldst) {
    __shared__ int cnt[256], cur[256], sbuf[256], svals[256];
    __shared__ int sorted[CAP + 2048];
    if (blockIdx.x < NBUCK) {
        int b = blockIdx.x, t = threadIdx.x;
        int nloc = min(256, NN - b * 256);
        int ecnt = min(cursor[b], CAP);
        size_t inBase = (size_t)b * CAP;
        // --- arena-start scan: conservative padded totals ----------------------
        if (t < 256) {
            int vv = 0;
            if (t < NBUCK) {
                int nl = min(256, NN - t * 256);
                vv = min(cursor[t], CAP) + 8 * nl;
            }
            svals[t] = vv;
        }
        __syncthreads();
        int* a = svals; int* bb = sbuf;
        for (int off = 1; off < 256; off <<= 1) {
            if (t < 256) bb[t] = a[t] + ((t >= off) ? a[t - off] : 0);
            __syncthreads();
            int* tmp = a; a = bb; bb = tmp;
        }
        int outBase = (b == 0) ? 0 : a[b - 1];
        __syncthreads();
        // --- per-dst histogram (self loop pre-counted) -------------------------
        if (t < 256) cnt[t] = (t < nloc) ? 1 : 0;
        __syncthreads();
        for (int i = t; i < ecnt; i += 1024) {
            unsigned u = bucketData[inBase + i];
            atomicAdd(&cnt[(u >> 16) & 255], 1);
        }
        __syncthreads();
        // --- scan of 8-padded per-dst counts -----------------------------------
        int cv = 0, pcv = 0;
        if (t < 256) {
            cv = cnt[t];
            pcv = (t < nloc) ? ((cv + 7) & ~7) : 0;
            sbuf[t] = pcv;
        }
        __syncthreads();
        a = sbuf; bb = cnt;
        for (int off = 1; off < 256; off <<= 1) {
            if (t < 256) bb[t] = a[t] + ((t >= off) ? a[t - off] : 0);
            __syncthreads();
            int* tmp = a; a = bb; bb = tmp;
        }
        int total = a[255];
        int excl = (t < 256) ? (a[t] - pcv) : 0;
        __syncthreads();
        if (t < nloc) {
            rowseg[b * 256 + t] = make_int2(outBase + excl, outBase + excl + pcv);
            sorted[excl] = b * 256 + t;              // self loop at slot 0
            for (int k = cv; k < pcv; k++) sorted[excl + k] = NN;  // sentinels
            cur[t] = excl + 1;
        }
        __syncthreads();
        for (int i = t; i < ecnt; i += 1024) {
            unsigned u = bucketData[inBase + i];
            int ld = (u >> 16) & 255;
            int p = atomicAdd(&cur[ld], 1);
            sorted[p] = (int)(u & 0xffffu);
        }
        __syncthreads();
        for (int i = t; i < total; i += 1024) srcs[outBase + i] = sorted[i];
        return;
    }
    // ---- gemm1: MFMA h1(fp16) = [x|topo] @ W1 + attention logits (16 waves)
    int wave = threadIdx.x >> 6, lane = threadIdx.x & 63;
    int row0 = (blockIdx.x - NBUCK) * 256 + wave * 16;
    if (row0 >= NN) return;
    int g = lane >> 4, li = lane & 15;
    int myrow = row0 + li;                        // A-operand row (m = lane&15)
    const half8* bp = (const half8*)Bf1;
    floatx4 acc[4] = {{0,0,0,0},{0,0,0,0},{0,0,0,0},{0,0,0,0}};
    #pragma unroll
    for (int kk = 0; kk < 4; kk++) {
        half8 Bv[4];
        #pragma unroll
        for (int ct = 0; ct < 4; ct++) Bv[ct] = bp[(kk * 4 + ct) * 64 + lane];
        int k0 = kk * 32 + g * 8;
        const float* sp = (k0 == 120) ? (topo + (size_t)myrow * 8)
                                      : (x + (size_t)myrow * 120 + k0);
        float4 u0 = ((const float4*)sp)[0];
        float4 u1 = ((const float4*)sp)[1];
        half8 av;
        av[0] = (_Float16)u0.x; av[1] = (_Float16)u0.y;
        av[2] = (_Float16)u0.z; av[3] = (_Float16)u0.w;
        av[4] = (_Float16)u1.x; av[5] = (_Float16)u1.y;
        av[6] = (_Float16)u1.z; av[7] = (_Float16)u1.w;
        #pragma unroll
        for (int ct = 0; ct < 4; ct++)
            acc[ct] = __builtin_amdgcn_mfma_f32_16x16x32_f16(av, Bv[ct], acc[ct], 0, 0, 0);
    }
    // C layout: col = ct*16+li, row = row0 + 4*g + r
    #pragma unroll
    for (int ct = 0; ct < 4; ct++)
        #pragma unroll
        for (int r = 0; r < 4; r++)
            h1[(size_t)(row0 + 4 * g + r) * 64 + ct * 16 + li] = __float2half(acc[ct][r]);
    // attention logits: head = 2*ct + (li>>3), dim = li&7
    float ps[4][4], pd[4][4];
    #pragma unroll
    for (int ct = 0; ct < 4; ct++) {
        int head = 2 * ct + (li >> 3), dix = li & 7;
        float asv = a_src[head * 8 + dix];
        float adv = a_dst[head * 8 + dix];
        #pragma unroll
        for (int r = 0; r < 4; r++) {
            ps[ct][r] = acc[ct][r] * asv;
            pd[ct][r] = acc[ct][r] * adv;
        }
    }
    #pragma unroll
    for (int off = 1; off <= 4; off <<= 1)
        #pragma unroll
        for (int ct = 0; ct < 4; ct++)
            #pragma unroll
            for (int r = 0; r < 4; r++) {
                ps[ct][r] += __shfl_xor(ps[ct][r], off, 64);
                pd[ct][r] += __shfl_xor(pd[ct][r], off, 64);
            }
    if ((li & 7) == 0) {
        #pragma unroll
        for (int ct = 0; ct < 4; ct++) {
            int head = 2 * ct + (li >> 3);
            #pragma unroll
            for (int r = 0; r < 4; r++) {
                int row = row0 + 4 * g + r;
                alsrc[row * 8 + head] = ps[ct][r];
                aldst[row * 8 + head] = pd[ct][r];
            }
        }
    }
}

// ------- layer 1 aggregation: 1 dst/wave, padded 8-wide segments, prefetch ------
__global__ __launch_bounds__(256) void k_agg1(
    const int2* __restrict__ rowseg, const int* __restrict__ srcs,
    const float* __restrict__ alsrc, const float* __restrict__ aldst,
    const __half* __restrict__ h1, const float* __restrict__ b1,
    __half* __restrict__ hout) {
    int wave = threadIdx.x >> 6;
    int lane = threadIdx.x & 63;
    int d = blockIdx.x * 4 + wave;
    if (d >= NN) return;
    int hs = lane >> 5;          // which edge of the pair
    int cp = lane & 31;          // col pair: cols 2cp, 2cp+1
    int hh = cp >> 2;            // head
    float adst = aldst[d * 8 + hh];
    int2 seg = rowseg[d];
    int jb = seg.x, je = seg.y;
    float ssum = 0.f, ax = 0.f, ay = 0.f;
    int sA0 = srcs[jb + hs],     sA1 = srcs[jb + 2 + hs];
    int sA2 = srcs[jb + 4 + hs], sA3 = srcs[jb + 6 + hs];
    for (int j = jb; j < je; j += 8) {
        int s0 = sA0, s1 = sA1, s2 = sA2, s3 = sA3;
        int jn = j + 8;
        if (jn < je) {           // wave-uniform branch
            sA0 = srcs[jn + hs];     sA1 = srcs[jn + 2 + hs];
            sA2 = srcs[jn + 4 + hs]; sA3 = srcs[jn + 6 + hs];
        }
        float e0 = alsrc[s0 * 8 + hh] + adst;
        float e1 = alsrc[s1 * 8 + hh] + adst;
        float e2 = alsrc[s2 * 8 + hh] + adst;
        float e3 = alsrc[s3 * 8 + hh] + adst;
        __half2 v0 = *(const __half2*)(h1 + (size_t)s0 * 64 + 2 * cp);
        __half2 v1 = *(const __half2*)(h1 + (size_t)s1 * 64 + 2 * cp);
        __half2 v2 = *(const __half2*)(h1 + (size_t)s2 * 64 + 2 * cp);
        __half2 v3 = *(const __half2*)(h1 + (size_t)s3 * 64 + 2 * cp);
        float p0 = __expf(fmaxf(e0, 0.2f * e0));
        float p1 = __expf(fmaxf(e1, 0.2f * e1));
        float p2 = __expf(fmaxf(e2, 0.2f * e2));
        float p3 = __expf(fmaxf(e3, 0.2f * e3));
        float2 f0 = __half22float2(v0), f1 = __half22float2(v1);
        float2 f2 = __half22float2(v2), f3 = __half22float2(v3);
        ssum += (p0 + p1) + (p2 + p3);
        ax += p0 * f0.x + p1 * f1.x + p2 * f2.x + p3 * f3.x;
        ay += p0 * f0.y + p1 * f1.y + p2 * f2.y + p3 * f3.y;
    }
    ssum += __shfl_xor(ssum, 32, 64);
    ax += __shfl_xor(ax, 32, 64);
    ay += __shfl_xor(ay, 32, 64);
    if (hs == 0) {
        float2 bv = *(const float2*)(b1 + 2 * cp);
        float inv = 1.f / ssum;
        float vx = ax * inv + bv.x;
        float vy = ay * inv + bv.y;
        vx = (vx > 0.f) ? vx : (__expf(vx) - 1.f);   // ELU
        vy = (vy > 0.f) ? vy : (__expf(vy) - 1.f);
        *(__half2*)(hout + (size_t)d * 64 + 2 * cp) = __floats2half2_rn(vx, vy);
    }
}

// ---------------- layer 2 node GEMM via MFMA (h2 fp16, 40 cols in 3 ctiles) -----
__global__ __launch_bounds__(256) void k_gemm2(
    const __half* __restrict__ hout, const _Float16* __restrict__ Bf2,
    const float* __restrict__ a_src2, const float* __restrict__ a_dst2,
    __half* __restrict__ h2, float* __restrict__ al2s, float* __restrict__ al2d) {
    int wave = threadIdx.x >> 6, lane = threadIdx.x & 63;
    int row0 = blockIdx.x * 64 + wave * 16;
    if (row0 >= NN) return;
    int g = lane >> 4, li = lane & 15;
    int myrow = row0 + li;
    half8 B[6];
    const half8* bp = (const half8*)Bf2;
    #pragma unroll
    for (int i = 0; i < 6; i++) B[i] = bp[i * 64 + lane];
    floatx4 acc[3] = {{0,0,0,0},{0,0,0,0},{0,0,0,0}};
    #pragma unroll
    for (int kk = 0; kk < 2; kk++) {
        int k0 = kk * 32 + g * 8;
        half8 av = *(const half8*)(hout + (size_t)myrow * 64 + k0);
        #pragma unroll
        for (int ct = 0; ct < 3; ct++)
            acc[ct] = __builtin_amdgcn_mfma_f32_16x16x32_f16(av, B[kk * 3 + ct], acc[ct], 0, 0, 0);
    }
    float ts[4] = {0.f, 0.f, 0.f, 0.f}, td[4] = {0.f, 0.f, 0.f, 0.f};
    #pragma unroll
    for (int ct = 0; ct < 3; ct++) {
        int col = ct * 16 + li;
        bool ok = (col < 40);
        float asv = ok ? a_src2[col] : 0.f;
        float adv = ok ? a_dst2[col] : 0.f;
        #pragma unroll
        for (int r = 0; r < 4; r++) {
            ts[r] += acc[ct][r] * asv;
            td[r] += acc[ct][r] * adv;
            if (ok) h2[(size_t)(row0 + 4 * g + r) * 40 + col] = __float2half(acc[ct][r]);
        }
    }
    #pragma unroll
    for (int off = 1; off <= 8; off <<= 1)
        #pragma unroll
        for (int r = 0; r < 4; r++) {
            ts[r] += __shfl_xor(ts[r], off, 64);
            td[r] += __shfl_xor(td[r], off, 64);
        }
    if (li == 0) {
        #pragma unroll
        for (int r = 0; r < 4; r++) {
            int row = row0 + 4 * g + r;
            al2s[row] = ts[r];
            al2d[row] = td[r];
        }
    }
}

// ------- layer 2 aggregation + fused log_softmax; padded segments, prefetch -----
__global__ __launch_bounds__(256) void k_agg2(
    const int2* __restrict__ rowseg, const int* __restrict__ srcs,
    const float* __restrict__ al2s, const float* __restrict__ al2d,
    const __half* __restrict__ h2, const float* __restrict__ b2,
    float* __restrict__ out) {
    int wave = threadIdx.x >> 6;
    int lane = threadIdx.x & 63;
    int d = blockIdx.x * 4 + wave;
    if (d >= NN) return;
    int hs = lane >> 5;
    int cp = lane & 31;              // cols 2cp,2cp+1; valid if cp<20
    bool act = (cp < 20);
    int cpc = act ? cp : 0;
    float adst = al2d[d];
    int2 seg = rowseg[d];
    int jb = seg.x, je = seg.y;
    float ssum = 0.f, ax = 0.f, ay = 0.f;
    int sA0 = srcs[jb + hs],     sA1 = srcs[jb + 2 + hs];
    int sA2 = srcs[jb + 4 + hs], sA3 = srcs[jb + 6 + hs];
    for (int j = jb; j < je; j += 8) {
        int s0 = sA0, s1 = sA1, s2 = sA2, s3 = sA3;
        int jn = j + 8;
        if (jn < je) {
            sA0 = srcs[jn + hs];     sA1 = srcs[jn + 2 + hs];
            sA2 = srcs[jn + 4 + hs]; sA3 = srcs[jn + 6 + hs];
        }
        float e0 = al2s[s0] + adst;
        float e1 = al2s[s1] + adst;
        float e2 = al2s[s2] + adst;
        float e3 = al2s[s3] + adst;
        __half2 v0 = *(const __half2*)(h2 + (size_t)s0 * 40 + 2 * cpc);
        __half2 v1 = *(const __half2*)(h2 + (size_t)s1 * 40 + 2 * cpc);
        __half2 v2 = *(const __half2*)(h2 + (size_t)s2 * 40 + 2 * cpc);
        __half2 v3 = *(const __half2*)(h2 + (size_t)s3 * 40 + 2 * cpc);
        float p0 = __expf(fmaxf(e0, 0.2f * e0));
        float p1 = __expf(fmaxf(e1, 0.2f * e1));
        float p2 = __expf(fmaxf(e2, 0.2f * e2));
        float p3 = __expf(fmaxf(e3, 0.2f * e3));
        float2 f0 = __half22float2(v0), f1 = __half22float2(v1);
        float2 f2 = __half22float2(v2), f3 = __half22float2(v3);
        ssum += (p0 + p1) + (p2 + p3);
        ax += p0 * f0.x + p1 * f1.x + p2 * f2.x + p3 * f3.x;
        ay += p0 * f0.y + p1 * f1.y + p2 * f2.y + p3 * f3.y;
    }
    ssum += __shfl_xor(ssum, 32, 64);
    ax += __shfl_xor(ax, 32, 64);
    ay += __shfl_xor(ay, 32, 64);
    float inv = 1.f / ssum;
    float2 bv = *(const float2*)(b2 + 2 * cpc);
    float ox = ax * inv + bv.x;
    float oy = ay * inv + bv.y;
    float mo = act ? fmaxf(ox, oy) : -3.0e38f;
    #pragma unroll
    for (int off = 16; off; off >>= 1) mo = fmaxf(mo, __shfl_xor(mo, off, 64));
    float te = act ? (__expf(ox - mo) + __expf(oy - mo)) : 0.f;
    #pragma unroll
    for (int off = 16; off; off >>= 1) te += __shfl_xor(te, off, 64);
    float ls = __logf(te);
    if (act && hs == 0)
        *(float2*)(out + (size_t)d * 40 + 2 * cp) = make_float2(ox - mo - ls, oy - mo - ls);
}

extern "C" void kernel_launch(void* const* d_in, const int* in_sizes, int n_in,
                              void* d_out, int out_size, void* d_ws, size_t ws_size,
                              hipStream_t stream) {
    (void)in_sizes; (void)n_in; (void)out_size; (void)ws_size;
    const float* x    = (const float*)d_in[0];
    const float* topo = (const float*)d_in[1];
    const int*   ei   = (const int*)d_in[2];
    const float* W1   = (const float*)d_in[3];
    const float* as1  = (const float*)d_in[4];
    const float* ad1  = (const float*)d_in[5];
    const float* b1   = (const float*)d_in[6];
    const float* W2   = (const float*)d_in[7];
    const float* as2  = (const float*)d_in[8];
    const float* ad2  = (const float*)d_in[9];
    const float* b2   = (const float*)d_in[10];
    float* out = (float*)d_out;

    char* ws = (char*)d_ws;
    size_t off = 0;
    auto alloc = [&](size_t bytes) {
        void* p = ws + off;
        off += (bytes + 255) / 256 * 256;
        return p;
    };
    int2*      rowseg     = (int2*)alloc((size_t)NN * 8);
    int*       cursor     = (int*)alloc(NBUCK * 4);
    unsigned*  bucketData = (unsigned*)alloc((size_t)NBUCK * CAP * 4);
    int*       srcs       = (int*)alloc((size_t)SRCS_MAX * 4);
    float*     alsrc1     = (float*)alloc((size_t)(NN + 1) * 8 * 4);
    float*     aldst1     = (float*)alloc((size_t)NN * 8 * 4);
    float*     al2s       = (float*)alloc((NN + 1) * 4);
    float*     al2d       = (float*)alloc(NN * 4);
    _Float16*  Bf1        = (_Float16*)alloc(4 * 4 * 64 * 8 * 2);
    _Float16*  Bf2        = (_Float16*)alloc(2 * 3 * 64 * 8 * 2);
    __half*    h1         = (__half*)alloc((size_t)(NN + 1) * 64 * 2);
    __half*    hout       = (__half*)alloc((size_t)NN * 64 * 2);
    __half*    h2         = (__half*)alloc((size_t)(NN + 1) * 40 * 2);

    hipMemsetAsync(cursor, 0, NBUCK * 4, stream);
    k_A     <<<NBA + 6,    256,  0, stream>>>(ei, cursor, bucketData, W1, W2,
                                              Bf1, Bf2, alsrc1, al2s);
    k_B     <<<NBUCK + 196, 1024, 0, stream>>>(bucketData, cursor, rowseg, srcs,
                                               x, topo, Bf1, as1, ad1, h1, alsrc1, aldst1);
    k_agg1  <<<(NN + 3) / 4, 256, 0, stream>>>(rowseg, srcs, alsrc1, aldst1, h1, b1, hout);
    k_gemm2 <<<782,        256,  0, stream>>>(hout, Bf2, as2, ad2, h2, al2s, al2d);
    k_agg2  <<<(NN + 3) / 4, 256, 0, stream>>>(rowseg, srcs, al2s, al2d, h2, b2, out);
}

// Round 10
// 175.277 us; speedup vs baseline: 1.0495x; 1.0495x over previous
//
#include <hip/hip_runtime.h>
#include <hip/hip_fp16.h>

#define NN 50000
#define EE 800000
#define NBUCK 196   // dst buckets of 256 nodes each
#define CAP 5120    // per-bucket edge capacity (mean ~4082, sigma ~64 -> 16 sigma)
#define TILEA 2048
#define NBA ((EE + TILEA - 1) / TILEA)   // 391
#define NGB 782     // ceil(50000/64) row blocks for MFMA gemm1
#define SRCS_MAX (EE + 8 * NN)           // padded CSR upper bound (1.2M)

typedef _Float16 half8 __attribute__((ext_vector_type(8)));
typedef float floatx4 __attribute__((ext_vector_type(4)));

// ---------- prep: W1/W2 -> fp16 MFMA B-fragments; zero cursor; sentinels --------
// Bf1[kk(4)][ct(4)][lane(64)][8]: B[n=ct*16+(L&15)][k=kk*32+(L>>4)*8+j]
// Bf2[kk(2)][ct(3)][lane(64)][8]: cols >= 40 zero-padded
__global__ void k_prep(const float* __restrict__ W1, const float* __restrict__ W2,
                       _Float16* __restrict__ Bf1, _Float16* __restrict__ Bf2,
                       int* __restrict__ cursor, float* __restrict__ alsrc,
                       float* __restrict__ al2s) {
    int tid = blockIdx.x * 256 + threadIdx.x;
    if (tid < 1024) {
        int kk = tid >> 8, ct = (tid >> 6) & 3, L = tid & 63;
        int k0 = kk * 32 + (L >> 4) * 8, col = ct * 16 + (L & 15);
        half8 v;
        #pragma unroll
        for (int j = 0; j < 8; j++) v[j] = (_Float16)W1[(k0 + j) * 64 + col];
        *(half8*)(Bf1 + ((size_t)((kk * 4 + ct) * 64 + L)) * 8) = v;
    } else if (tid < 1024 + 384) {
        int u = tid - 1024;
        int kk = u / 192, rem = u % 192;
        int ct = rem >> 6, L = rem & 63;
        int k0 = kk * 32 + (L >> 4) * 8, col = ct * 16 + (L & 15);
        half8 v;
        #pragma unroll
        for (int j = 0; j < 8; j++)
            v[j] = (col < 40) ? (_Float16)W2[(k0 + j) * 40 + col] : (_Float16)0.f;
        *(half8*)(Bf2 + ((size_t)((kk * 3 + ct) * 64 + L)) * 8) = v;
    } else {
        int u = tid - 1408;
        if (u < NBUCK) cursor[u] = 0;
        if (u >= 200 && u < 208) alsrc[(size_t)NN * 8 + (u - 200)] = -1e30f;
        if (u == 208) al2s[NN] = -1e30f;
    }
}

// ---------- FUSED independent stage: blocks [0,NBA) bucketA, [NBA,NBA+NGB) gemm1
__global__ __launch_bounds__(256) void k_fusedAG(
    const int* __restrict__ ei, int* __restrict__ cursor,
    unsigned* __restrict__ bucketData,
    const float* __restrict__ x, const float* __restrict__ topo,
    const _Float16* __restrict__ Bf1,
    const float* __restrict__ a_src, const float* __restrict__ a_dst,
    __half* __restrict__ h1, float* __restrict__ alsrc, float* __restrict__ aldst) {
    if (blockIdx.x < NBA) {
        // ---- bucketA: coarse bucket by dst>>8, LDS-staged, coalesced-run writes
        __shared__ int cnt[NBUCK], base[NBUCK];
        int t = threadIdx.x;
        for (int i = t; i < NBUCK; i += 256) cnt[i] = 0;
        __syncthreads();
        int e0 = blockIdx.x * TILEA;
        int nE = min(TILEA, EE - e0);
        unsigned pk[8]; int bk[8], rk[8];
        int m = 0;
        for (int i = t; i < nE; i += 256) {
            int e = e0 + i;
            int s = ei[e], d = ei[EE + e];
            pk[m] = ((unsigned)d << 16) | (unsigned)s;
            bk[m] = d >> 8;
            rk[m] = atomicAdd(&cnt[bk[m]], 1);
            m++;
        }
        __syncthreads();
        for (int i = t; i < NBUCK; i += 256)
            base[i] = (cnt[i] > 0) ? atomicAdd(&cursor[i], cnt[i]) : 0;
        __syncthreads();
        for (int k = 0; k < m; k++) {
            int pos = base[bk[k]] + rk[k];
            if (pos < CAP) bucketData[(size_t)bk[k] * CAP + pos] = pk[k];
        }
        return;
    }
    // ---- gemm1: MFMA h1(fp16) = [x|topo] @ W1 + attention logits
    int wave = threadIdx.x >> 6, lane = threadIdx.x & 63;
    int row0 = (blockIdx.x - NBA) * 64 + wave * 16;
    if (row0 >= NN) return;
    int g = lane >> 4, li = lane & 15;
    int myrow = row0 + li;                        // A-operand row (m = lane&15)
    half8 B[16];
    const half8* bp = (const half8*)Bf1;
    #pragma unroll
    for (int i = 0; i < 16; i++) B[i] = bp[i * 64 + lane];
    floatx4 acc[4] = {{0,0,0,0},{0,0,0,0},{0,0,0,0},{0,0,0,0}};
    #pragma unroll
    for (int kk = 0; kk < 4; kk++) {
        int k0 = kk * 32 + g * 8;
        const float* sp = (k0 == 120) ? (topo + (size_t)myrow * 8)
                                      : (x + (size_t)myrow * 120 + k0);
        float4 u0 = ((const float4*)sp)[0];
        float4 u1 = ((const float4*)sp)[1];
        half8 av;
        av[0] = (_Float16)u0.x; av[1] = (_Float16)u0.y;
        av[2] = (_Float16)u0.z; av[3] = (_Float16)u0.w;
        av[4] = (_Float16)u1.x; av[5] = (_Float16)u1.y;
        av[6] = (_Float16)u1.z; av[7] = (_Float16)u1.w;
        #pragma unroll
        for (int ct = 0; ct < 4; ct++)
            acc[ct] = __builtin_amdgcn_mfma_f32_16x16x32_f16(av, B[kk * 4 + ct], acc[ct], 0, 0, 0);
    }
    // C layout: col = ct*16+li, row = row0 + 4*g + r
    #pragma unroll
    for (int ct = 0; ct < 4; ct++)
        #pragma unroll
        for (int r = 0; r < 4; r++)
            h1[(size_t)(row0 + 4 * g + r) * 64 + ct * 16 + li] = __float2half(acc[ct][r]);
    // attention logits: head = 2*ct + (li>>3), dim = li&7 (heads are 8-col aligned)
    float ps[4][4], pd[4][4];
    #pragma unroll
    for (int ct = 0; ct < 4; ct++) {
        int head = 2 * ct + (li >> 3), dix = li & 7;
        float asv = a_src[head * 8 + dix];
        float adv = a_dst[head * 8 + dix];
        #pragma unroll
        for (int r = 0; r < 4; r++) {
            ps[ct][r] = acc[ct][r] * asv;
            pd[ct][r] = acc[ct][r] * adv;
        }
    }
    #pragma unroll
    for (int off = 1; off <= 4; off <<= 1)
        #pragma unroll
        for (int ct = 0; ct < 4; ct++)
            #pragma unroll
            for (int r = 0; r < 4; r++) {
                ps[ct][r] += __shfl_xor(ps[ct][r], off, 64);
                pd[ct][r] += __shfl_xor(pd[ct][r], off, 64);
            }
    if ((li & 7) == 0) {
        #pragma unroll
        for (int ct = 0; ct < 4; ct++) {
            int head = 2 * ct + (li >> 3);
            #pragma unroll
            for (int r = 0; r < 4; r++) {
                int row = row0 + 4 * g + r;
                alsrc[row * 8 + head] = ps[ct][r];
                aldst[row * 8 + head] = pd[ct][r];
            }
        }
    }
}

// ---------- Pass B (1024 threads): inline arena scan + per-bucket counting sort -
__global__ __launch_bounds__(1024) void k_bucketB(const unsigned* __restrict__ bucketData,
        const int* __restrict__ cursor,
        int2* __restrict__ rowseg, int* __restrict__ srcs) {
    __shared__ int cnt[256], cur[256], sbuf[256], svals[256];
    __shared__ int sorted[CAP + 2048];
    int b = blockIdx.x, t = threadIdx.x;
    int nloc = min(256, NN - b * 256);
    int ecnt = min(cursor[b], CAP);
    size_t inBase = (size_t)b * CAP;
    // --- arena-start scan: conservative padded totals --------------------------
    if (t < 256) {
        int vv = 0;
        if (t < NBUCK) {
            int nl = min(256, NN - t * 256);
            vv = min(cursor[t], CAP) + 8 * nl;
        }
        svals[t] = vv;
    }
    __syncthreads();
    int* a = svals; int* bb = sbuf;
    for (int off = 1; off < 256; off <<= 1) {
        if (t < 256) bb[t] = a[t] + ((t >= off) ? a[t - off] : 0);
        __syncthreads();
        int* tmp = a; a = bb; bb = tmp;
    }
    int outBase = (b == 0) ? 0 : a[b - 1];
    __syncthreads();
    // --- per-dst histogram (self loop pre-counted) -----------------------------
    if (t < 256) cnt[t] = (t < nloc) ? 1 : 0;
    __syncthreads();
    for (int i = t; i < ecnt; i += 1024) {
        unsigned u = bucketData[inBase + i];
        atomicAdd(&cnt[(u >> 16) & 255], 1);
    }
    __syncthreads();
    // --- scan of 8-padded per-dst counts ---------------------------------------
    int cv = 0, pcv = 0;
    if (t < 256) {
        cv = cnt[t];
        pcv = (t < nloc) ? ((cv + 7) & ~7) : 0;
        sbuf[t] = pcv;
    }
    __syncthreads();
    a = sbuf; bb = cnt;
    for (int off = 1; off < 256; off <<= 1) {
        if (t < 256) bb[t] = a[t] + ((t >= off) ? a[t - off] : 0);
        __syncthreads();
        int* tmp = a; a = bb; bb = tmp;
    }
    int total = a[255];
    int excl = (t < 256) ? (a[t] - pcv) : 0;
    __syncthreads();
    if (t < nloc) {
        rowseg[b * 256 + t] = make_int2(outBase + excl, outBase + excl + pcv);
        sorted[excl] = b * 256 + t;              // self loop at slot 0 of segment
        for (int k = cv; k < pcv; k++) sorted[excl + k] = NN;  // sentinel pads
        cur[t] = excl + 1;
    }
    __syncthreads();
    for (int i = t; i < ecnt; i += 1024) {
        unsigned u = bucketData[inBase + i];
        int ld = (u >> 16) & 255;
        int p = atomicAdd(&cur[ld], 1);
        sorted[p] = (int)(u & 0xffffu);
    }
    __syncthreads();
    for (int i = t; i < total; i += 1024) srcs[outBase + i] = sorted[i];
}

// ------- layer 1 aggregation: 1 dst/wave, padded 8-wide segments, prefetch ------
__global__ __launch_bounds__(256) void k_agg1(
    const int2* __restrict__ rowseg, const int* __restrict__ srcs,
    const float* __restrict__ alsrc, const float* __restrict__ aldst,
    const __half* __restrict__ h1, const float* __restrict__ b1,
    __half* __restrict__ hout) {
    int wave = threadIdx.x >> 6;
    int lane = threadIdx.x & 63;
    int d = blockIdx.x * 4 + wave;
    if (d >= NN) return;
    int hs = lane >> 5;          // which edge of the pair
    int cp = lane & 31;          // col pair: cols 2cp, 2cp+1
    int hh = cp >> 2;            // head
    float adst = aldst[d * 8 + hh];
    int2 seg = rowseg[d];
    int jb = seg.x, je = seg.y;
    float ssum = 0.f, ax = 0.f, ay = 0.f;
    int sA0 = srcs[jb + hs],     sA1 = srcs[jb + 2 + hs];
    int sA2 = srcs[jb + 4 + hs], sA3 = srcs[jb + 6 + hs];
    for (int j = jb; j < je; j += 8) {
        int s0 = sA0, s1 = sA1, s2 = sA2, s3 = sA3;
        int jn = j + 8;
        if (jn < je) {           // wave-uniform branch
            sA0 = srcs[jn + hs];     sA1 = srcs[jn + 2 + hs];
            sA2 = srcs[jn + 4 + hs]; sA3 = srcs[jn + 6 + hs];
        }
        float e0 = alsrc[s0 * 8 + hh] + adst;
        float e1 = alsrc[s1 * 8 + hh] + adst;
        float e2 = alsrc[s2 * 8 + hh] + adst;
        float e3 = alsrc[s3 * 8 + hh] + adst;
        __half2 v0 = *(const __half2*)(h1 + (size_t)s0 * 64 + 2 * cp);
        __half2 v1 = *(const __half2*)(h1 + (size_t)s1 * 64 + 2 * cp);
        __half2 v2 = *(const __half2*)(h1 + (size_t)s2 * 64 + 2 * cp);
        __half2 v3 = *(const __half2*)(h1 + (size_t)s3 * 64 + 2 * cp);
        float p0 = __expf(fmaxf(e0, 0.2f * e0));
        float p1 = __expf(fmaxf(e1, 0.2f * e1));
        float p2 = __expf(fmaxf(e2, 0.2f * e2));
        float p3 = __expf(fmaxf(e3, 0.2f * e3));
        float2 f0 = __half22float2(v0), f1 = __half22float2(v1);
        float2 f2 = __half22float2(v2), f3 = __half22float2(v3);
        ssum += (p0 + p1) + (p2 + p3);
        ax += p0 * f0.x + p1 * f1.x + p2 * f2.x + p3 * f3.x;
        ay += p0 * f0.y + p1 * f1.y + p2 * f2.y + p3 * f3.y;
    }
    ssum += __shfl_xor(ssum, 32, 64);
    ax += __shfl_xor(ax, 32, 64);
    ay += __shfl_xor(ay, 32, 64);
    if (hs == 0) {
        float2 bv = *(const float2*)(b1 + 2 * cp);
        float inv = 1.f / ssum;
        float vx = ax * inv + bv.x;
        float vy = ay * inv + bv.y;
        vx = (vx > 0.f) ? vx : (__expf(vx) - 1.f);   // ELU
        vy = (vy > 0.f) ? vy : (__expf(vy) - 1.f);
        *(__half2*)(hout + (size_t)d * 64 + 2 * cp) = __floats2half2_rn(vx, vy);
    }
}

// ---------------- layer 2 node GEMM via MFMA (h2 fp16, 40 cols in 3 ctiles) -----
__global__ __launch_bounds__(256) void k_gemm2(
    const __half* __restrict__ hout, const _Float16* __restrict__ Bf2,
    const float* __restrict__ a_src2, const float* __restrict__ a_dst2,
    __half* __restrict__ h2, float* __restrict__ al2s, float* __restrict__ al2d) {
    int wave = threadIdx.x >> 6, lane = threadIdx.x & 63;
    int row0 = blockIdx.x * 64 + wave * 16;
    if (row0 >= NN) return;
    int g = lane >> 4, li = lane & 15;
    int myrow = row0 + li;
    half8 B[6];
    const half8* bp = (const half8*)Bf2;
    #pragma unroll
    for (int i = 0; i < 6; i++) B[i] = bp[i * 64 + lane];
    floatx4 acc[3] = {{0,0,0,0},{0,0,0,0},{0,0,0,0}};
    #pragma unroll
    for (int kk = 0; kk < 2; kk++) {
        int k0 = kk * 32 + g * 8;
        half8 av = *(const half8*)(hout + (size_t)myrow * 64 + k0);
        #pragma unroll
        for (int ct = 0; ct < 3; ct++)
            acc[ct] = __builtin_amdgcn_mfma_f32_16x16x32_f16(av, B[kk * 3 + ct], acc[ct], 0, 0, 0);
    }
    float ts[4] = {0.f, 0.f, 0.f, 0.f}, td[4] = {0.f, 0.f, 0.f, 0.f};
    #pragma unroll
    for (int ct = 0; ct < 3; ct++) {
        int col = ct * 16 + li;
        bool ok = (col < 40);
        float asv = ok ? a_src2[col] : 0.f;
        float adv = ok ? a_dst2[col] : 0.f;
        #pragma unroll
        for (int r = 0; r < 4; r++) {
            ts[r] += acc[ct][r] * asv;
            td[r] += acc[ct][r] * adv;
            if (ok) h2[(size_t)(row0 + 4 * g + r) * 40 + col] = __float2half(acc[ct][r]);
        }
    }
    #pragma unroll
    for (int off = 1; off <= 8; off <<= 1)
        #pragma unroll
        for (int r = 0; r < 4; r++) {
            ts[r] += __shfl_xor(ts[r], off, 64);
            td[r] += __shfl_xor(td[r], off, 64);
        }
    if (li == 0) {
        #pragma unroll
        for (int r = 0; r < 4; r++) {
            int row = row0 + 4 * g + r;
            al2s[row] = ts[r];
            al2d[row] = td[r];
        }
    }
}

// ------- layer 2 aggregation + fused log_softmax; padded segments, prefetch -----
__global__ __launch_bounds__(256) void k_agg2(
    const int2* __restrict__ rowseg, const int* __restrict__ srcs,
    const float* __restrict__ al2s, const float* __restrict__ al2d,
    const __half* __restrict__ h2, const float* __restrict__ b2,
    float* __restrict__ out) {
    int wave = threadIdx.x >> 6;
    int lane = threadIdx.x & 63;
    int d = blockIdx.x * 4 + wave;
    if (d >= NN) return;
    int hs = lane >> 5;
    int cp = lane & 31;              // cols 2cp,2cp+1; valid if cp<20
    bool act = (cp < 20);
    int cpc = act ? cp : 0;
    float adst = al2d[d];
    int2 seg = rowseg[d];
    int jb = seg.x, je = seg.y;
    float ssum = 0.f, ax = 0.f, ay = 0.f;
    int sA0 = srcs[jb + hs],     sA1 = srcs[jb + 2 + hs];
    int sA2 = srcs[jb + 4 + hs], sA3 = srcs[jb + 6 + hs];
    for (int j = jb; j < je; j += 8) {
        int s0 = sA0, s1 = sA1, s2 = sA2, s3 = sA3;
        int jn = j + 8;
        if (jn < je) {
            sA0 = srcs[jn + hs];     sA1 = srcs[jn + 2 + hs];
            sA2 = srcs[jn + 4 + hs]; sA3 = srcs[jn + 6 + hs];
        }
        float e0 = al2s[s0] + adst;
        float e1 = al2s[s1] + adst;
        float e2 = al2s[s2] + adst;
        float e3 = al2s[s3] + adst;
        __half2 v0 = *(const __half2*)(h2 + (size_t)s0 * 40 + 2 * cpc);
        __half2 v1 = *(const __half2*)(h2 + (size_t)s1 * 40 + 2 * cpc);
        __half2 v2 = *(const __half2*)(h2 + (size_t)s2 * 40 + 2 * cpc);
        __half2 v3 = *(const __half2*)(h2 + (size_t)s3 * 40 + 2 * cpc);
        float p0 = __expf(fmaxf(e0, 0.2f * e0));
        float p1 = __expf(fmaxf(e1, 0.2f * e1));
        float p2 = __expf(fmaxf(e2, 0.2f * e2));
        float p3 = __expf(fmaxf(e3, 0.2f * e3));
        float2 f0 = __half22float2(v0), f1 = __half22float2(v1);
        float2 f2 = __half22float2(v2), f3 = __half22float2(v3);
        ssum += (p0 + p1) + (p2 + p3);
        ax += p0 * f0.x + p1 * f1.x + p2 * f2.x + p3 * f3.x;
        ay += p0 * f0.y + p1 * f1.y + p2 * f2.y + p3 * f3.y;
    }
    ssum += __shfl_xor(ssum, 32, 64);
    ax += __shfl_xor(ax, 32, 64);
    ay += __shfl_xor(ay, 32, 64);
    float inv = 1.f / ssum;
    float2 bv = *(const float2*)(b2 + 2 * cpc);
    float ox = ax * inv + bv.x;
    float oy = ay * inv + bv.y;
    float mo = act ? fmaxf(ox, oy) : -3.0e38f;
    #pragma unroll
    for (int off = 16; off; off >>= 1) mo = fmaxf(mo, __shfl_xor(mo, off, 64));
    float te = act ? (__expf(ox - mo) + __expf(oy - mo)) : 0.f;
    #pragma unroll
    for (int off = 16; off; off >>= 1) te += __shfl_xor(te, off, 64);
    float ls = __logf(te);
    if (act && hs == 0)
        *(float2*)(out + (size_t)d * 40 + 2 * cp) = make_float2(ox - mo - ls, oy - mo - ls);
}

extern "C" void kernel_launch(void* const* d_in, const int* in_sizes, int n_in,
                              void* d_out, int out_size, void* d_ws, size_t ws_size,
                              hipStream_t stream) {
    (void)in_sizes; (void)n_in; (void)out_size; (void)ws_size;
    const float* x    = (const float*)d_in[0];
    const float* topo = (const float*)d_in[1];
    const int*   ei   = (const int*)d_in[2];
    const float* W1   = (const float*)d_in[3];
    const float* as1  = (const float*)d_in[4];
    const float* ad1  = (const float*)d_in[5];
    const float* b1   = (const float*)d_in[6];
    const float* W2   = (const float*)d_in[7];
    const float* as2  = (const float*)d_in[8];
    const float* ad2  = (const float*)d_in[9];
    const float* b2   = (const float*)d_in[10];
    float* out = (float*)d_out;

    char* ws = (char*)d_ws;
    size_t off = 0;
    auto alloc = [&](size_t bytes) {
        void* p = ws + off;
        off += (bytes + 255) / 256 * 256;
        return p;
    };
    int2*      rowseg     = (int2*)alloc((size_t)NN * 8);
    int*       cursor     = (int*)alloc(NBUCK * 4);
    unsigned*  bucketData = (unsigned*)alloc((size_t)NBUCK * CAP * 4);
    int*       srcs       = (int*)alloc((size_t)SRCS_MAX * 4);
    float*     alsrc1     = (float*)alloc((size_t)(NN + 1) * 8 * 4);
    float*     aldst1     = (float*)alloc((size_t)NN * 8 * 4);
    float*     al2s       = (float*)alloc((NN + 1) * 4);
    float*     al2d       = (float*)alloc(NN * 4);
    _Float16*  Bf1        = (_Float16*)alloc(4 * 4 * 64 * 8 * 2);
    _Float16*  Bf2        = (_Float16*)alloc(2 * 3 * 64 * 8 * 2);
    __half*    h1         = (__half*)alloc((size_t)(NN + 1) * 64 * 2);
    __half*    hout       = (__half*)alloc((size_t)NN * 64 * 2);
    __half*    h2         = (__half*)alloc((size_t)(NN + 1) * 40 * 2);

    k_prep    <<<7,         256,  0, stream>>>(W1, W2, Bf1, Bf2, cursor, alsrc1, al2s);
    k_fusedAG <<<NBA + NGB, 256,  0, stream>>>(ei, cursor, bucketData,
                                               x, topo, Bf1, as1, ad1, h1, alsrc1, aldst1);
    k_bucketB <<<NBUCK,     1024, 0, stream>>>(bucketData, cursor, rowseg, srcs);
    k_agg1    <<<(NN + 3) / 4, 256, 0, stream>>>(rowseg, srcs, alsrc1, aldst1, h1, b1, hout);
    k_gemm2   <<<782,       256,  0, stream>>>(hout, Bf2, as2, ad2, h2, al2s, al2d);
    k_agg2    <<<(NN + 3) / 4, 256, 0, stream>>>(rowseg, srcs, al2s, al2d, h2, b2, out);
}

// Round 11
// 174.747 us; speedup vs baseline: 1.0527x; 1.0030x over previous
//
#include <hip/hip_runtime.h>
#include <hip/hip_fp16.h>

#define NN 50000
#define EE 800000
#define NBUCK 196   // dst buckets of 256 nodes each
#define CAP 5120    // per-bucket edge capacity (mean ~4082, sigma ~64 -> 16 sigma)
#define TILEA 2048
#define NBA ((EE + TILEA - 1) / TILEA)   // 391
#define NGB 782     // ceil(50000/64) row blocks for MFMA gemm1
#define SRCS_MAX (EE + 8 * NN)           // padded CSR upper bound (1.2M)

typedef _Float16 half8 __attribute__((ext_vector_type(8)));
typedef float floatx4 __attribute__((ext_vector_type(4)));
typedef float floatx2 __attribute__((ext_vector_type(2)));

// fp8 e4m3 (OCP) helpers — gfx950 native converts
__device__ __forceinline__ unsigned char f32_to_fp8(float a) {
    int r = __builtin_amdgcn_cvt_pk_fp8_f32(a, a, 0, false);
    return (unsigned char)(r & 0xff);
}
__device__ __forceinline__ float2 fp8pair_to_f32(unsigned v) {
    floatx2 r = __builtin_amdgcn_cvt_pk_f32_fp8(v, false);
    return make_float2(r[0], r[1]);
}

// ---------- prep: W1/W2 -> fp16 MFMA B-fragments; zero cursor; sentinels --------
// Bf1[kk(4)][ct(4)][lane(64)][8]: B[n=ct*16+(L&15)][k=kk*32+(L>>4)*8+j]
// Bf2[kk(2)][ct(3)][lane(64)][8]: cols >= 40 zero-padded
__global__ void k_prep(const float* __restrict__ W1, const float* __restrict__ W2,
                       _Float16* __restrict__ Bf1, _Float16* __restrict__ Bf2,
                       int* __restrict__ cursor, float* __restrict__ alsrc,
                       float* __restrict__ al2s) {
    int tid = blockIdx.x * 256 + threadIdx.x;
    if (tid < 1024) {
        int kk = tid >> 8, ct = (tid >> 6) & 3, L = tid & 63;
        int k0 = kk * 32 + (L >> 4) * 8, col = ct * 16 + (L & 15);
        half8 v;
        #pragma unroll
        for (int j = 0; j < 8; j++) v[j] = (_Float16)W1[(k0 + j) * 64 + col];
        *(half8*)(Bf1 + ((size_t)((kk * 4 + ct) * 64 + L)) * 8) = v;
    } else if (tid < 1024 + 384) {
        int u = tid - 1024;
        int kk = u / 192, rem = u % 192;
        int ct = rem >> 6, L = rem & 63;
        int k0 = kk * 32 + (L >> 4) * 8, col = ct * 16 + (L & 15);
        half8 v;
        #pragma unroll
        for (int j = 0; j < 8; j++)
            v[j] = (col < 40) ? (_Float16)W2[(k0 + j) * 40 + col] : (_Float16)0.f;
        *(half8*)(Bf2 + ((size_t)((kk * 3 + ct) * 64 + L)) * 8) = v;
    } else {
        int u = tid - 1408;
        if (u < NBUCK) cursor[u] = 0;
        if (u >= 200 && u < 208) alsrc[(size_t)NN * 8 + (u - 200)] = -1e30f;
        if (u == 208) al2s[NN] = -1e30f;
    }
}

// ---------- FUSED independent stage: blocks [0,NBA) bucketA, [NBA,NBA+NGB) gemm1
__global__ __launch_bounds__(256) void k_fusedAG(
    const int* __restrict__ ei, int* __restrict__ cursor,
    unsigned* __restrict__ bucketData,
    const float* __restrict__ x, const float* __restrict__ topo,
    const _Float16* __restrict__ Bf1,
    const float* __restrict__ a_src, const float* __restrict__ a_dst,
    unsigned char* __restrict__ h1, float* __restrict__ alsrc, float* __restrict__ aldst) {
    if (blockIdx.x < NBA) {
        // ---- bucketA: coarse bucket by dst>>8, LDS-staged, coalesced-run writes
        __shared__ int cnt[NBUCK], base[NBUCK];
        int t = threadIdx.x;
        for (int i = t; i < NBUCK; i += 256) cnt[i] = 0;
        __syncthreads();
        int e0 = blockIdx.x * TILEA;
        int nE = min(TILEA, EE - e0);
        unsigned pk[8]; int bk[8], rk[8];
        int m = 0;
        for (int i = t; i < nE; i += 256) {
            int e = e0 + i;
            int s = ei[e], d = ei[EE + e];
            pk[m] = ((unsigned)d << 16) | (unsigned)s;
            bk[m] = d >> 8;
            rk[m] = atomicAdd(&cnt[bk[m]], 1);
            m++;
        }
        __syncthreads();
        for (int i = t; i < NBUCK; i += 256)
            base[i] = (cnt[i] > 0) ? atomicAdd(&cursor[i], cnt[i]) : 0;
        __syncthreads();
        for (int k = 0; k < m; k++) {
            int pos = base[bk[k]] + rk[k];
            if (pos < CAP) bucketData[(size_t)bk[k] * CAP + pos] = pk[k];
        }
        return;
    }
    // ---- gemm1: MFMA h1(fp8 e4m3) = [x|topo] @ W1 + attention logits (fp32)
    int wave = threadIdx.x >> 6, lane = threadIdx.x & 63;
    int row0 = (blockIdx.x - NBA) * 64 + wave * 16;
    if (row0 >= NN) return;
    int g = lane >> 4, li = lane & 15;
    int myrow = row0 + li;                        // A-operand row (m = lane&15)
    half8 B[16];
    const half8* bp = (const half8*)Bf1;
    #pragma unroll
    for (int i = 0; i < 16; i++) B[i] = bp[i * 64 + lane];
    floatx4 acc[4] = {{0,0,0,0},{0,0,0,0},{0,0,0,0},{0,0,0,0}};
    #pragma unroll
    for (int kk = 0; kk < 4; kk++) {
        int k0 = kk * 32 + g * 8;
        const float* sp = (k0 == 120) ? (topo + (size_t)myrow * 8)
                                      : (x + (size_t)myrow * 120 + k0);
        float4 u0 = ((const float4*)sp)[0];
        float4 u1 = ((const float4*)sp)[1];
        half8 av;
        av[0] = (_Float16)u0.x; av[1] = (_Float16)u0.y;
        av[2] = (_Float16)u0.z; av[3] = (_Float16)u0.w;
        av[4] = (_Float16)u1.x; av[5] = (_Float16)u1.y;
        av[6] = (_Float16)u1.z; av[7] = (_Float16)u1.w;
        #pragma unroll
        for (int ct = 0; ct < 4; ct++)
            acc[ct] = __builtin_amdgcn_mfma_f32_16x16x32_f16(av, B[kk * 4 + ct], acc[ct], 0, 0, 0);
    }
    // C layout: col = ct*16+li, row = row0 + 4*g + r
    #pragma unroll
    for (int ct = 0; ct < 4; ct++)
        #pragma unroll
        for (int r = 0; r < 4; r++)
            h1[(size_t)(row0 + 4 * g + r) * 64 + ct * 16 + li] = f32_to_fp8(acc[ct][r]);
    // attention logits: head = 2*ct + (li>>3), dim = li&7 (heads are 8-col aligned)
    float ps[4][4], pd[4][4];
    #pragma unroll
    for (int ct = 0; ct < 4; ct++) {
        int head = 2 * ct + (li >> 3), dix = li & 7;
        float asv = a_src[head * 8 + dix];
        float adv = a_dst[head * 8 + dix];
        #pragma unroll
        for (int r = 0; r < 4; r++) {
            ps[ct][r] = acc[ct][r] * asv;
            pd[ct][r] = acc[ct][r] * adv;
        }
    }
    #pragma unroll
    for (int off = 1; off <= 4; off <<= 1)
        #pragma unroll
        for (int ct = 0; ct < 4; ct++)
            #pragma unroll
            for (int r = 0; r < 4; r++) {
                ps[ct][r] += __shfl_xor(ps[ct][r], off, 64);
                pd[ct][r] += __shfl_xor(pd[ct][r], off, 64);
            }
    if ((li & 7) == 0) {
        #pragma unroll
        for (int ct = 0; ct < 4; ct++) {
            int head = 2 * ct + (li >> 3);
            #pragma unroll
            for (int r = 0; r < 4; r++) {
                int row = row0 + 4 * g + r;
                alsrc[row * 8 + head] = ps[ct][r];
                aldst[row * 8 + head] = pd[ct][r];
            }
        }
    }
}

// ---------- Pass B (1024 threads): inline arena scan + per-bucket counting sort -
__global__ __launch_bounds__(1024) void k_bucketB(const unsigned* __restrict__ bucketData,
        const int* __restrict__ cursor,
        int2* __restrict__ rowseg, int* __restrict__ srcs) {
    __shared__ int cnt[256], cur[256], sbuf[256], svals[256];
    __shared__ int sorted[CAP + 2048];
    int b = blockIdx.x, t = threadIdx.x;
    int nloc = min(256, NN - b * 256);
    int ecnt = min(cursor[b], CAP);
    size_t inBase = (size_t)b * CAP;
    // --- arena-start scan: conservative padded totals --------------------------
    if (t < 256) {
        int vv = 0;
        if (t < NBUCK) {
            int nl = min(256, NN - t * 256);
            vv = min(cursor[t], CAP) + 8 * nl;
        }
        svals[t] = vv;
    }
    __syncthreads();
    int* a = svals; int* bb = sbuf;
    for (int off = 1; off < 256; off <<= 1) {
        if (t < 256) bb[t] = a[t] + ((t >= off) ? a[t - off] : 0);
        __syncthreads();
        int* tmp = a; a = bb; bb = tmp;
    }
    int outBase = (b == 0) ? 0 : a[b - 1];
    __syncthreads();
    // --- per-dst histogram (self loop pre-counted) -----------------------------
    if (t < 256) cnt[t] = (t < nloc) ? 1 : 0;
    __syncthreads();
    for (int i = t; i < ecnt; i += 1024) {
        unsigned u = bucketData[inBase + i];
        atomicAdd(&cnt[(u >> 16) & 255], 1);
    }
    __syncthreads();
    // --- scan of 8-padded per-dst counts ---------------------------------------
    int cv = 0, pcv = 0;
    if (t < 256) {
        cv = cnt[t];
        pcv = (t < nloc) ? ((cv + 7) & ~7) : 0;
        sbuf[t] = pcv;
    }
    __syncthreads();
    a = sbuf; bb = cnt;
    for (int off = 1; off < 256; off <<= 1) {
        if (t < 256) bb[t] = a[t] + ((t >= off) ? a[t - off] : 0);
        __syncthreads();
        int* tmp = a; a = bb; bb = tmp;
    }
    int total = a[255];
    int excl = (t < 256) ? (a[t] - pcv) : 0;
    __syncthreads();
    if (t < nloc) {
        rowseg[b * 256 + t] = make_int2(outBase + excl, outBase + excl + pcv);
        sorted[excl] = b * 256 + t;              // self loop at slot 0 of segment
        for (int k = cv; k < pcv; k++) sorted[excl + k] = NN;  // sentinel pads
        cur[t] = excl + 1;
    }
    __syncthreads();
    for (int i = t; i < ecnt; i += 1024) {
        unsigned u = bucketData[inBase + i];
        int ld = (u >> 16) & 255;
        int p = atomicAdd(&cur[ld], 1);
        sorted[p] = (int)(u & 0xffffu);
    }
    __syncthreads();
    for (int i = t; i < total; i += 1024) srcs[outBase + i] = sorted[i];
}

// ------- layer 1 aggregation: 1 dst/wave, padded 8-wide segments, fp8 values ----
__global__ __launch_bounds__(256) void k_agg1(
    const int2* __restrict__ rowseg, const int* __restrict__ srcs,
    const float* __restrict__ alsrc, const float* __restrict__ aldst,
    const unsigned char* __restrict__ h1, const float* __restrict__ b1,
    __half* __restrict__ hout) {
    int wave = threadIdx.x >> 6;
    int lane = threadIdx.x & 63;
    int d = blockIdx.x * 4 + wave;
    if (d >= NN) return;
    int hs = lane >> 5;          // which edge of the pair
    int cp = lane & 31;          // col pair: cols 2cp, 2cp+1
    int hh = cp >> 2;            // head
    float adst = aldst[d * 8 + hh];
    int2 seg = rowseg[d];
    int jb = seg.x, je = seg.y;
    float ssum = 0.f, ax = 0.f, ay = 0.f;
    int sA0 = srcs[jb + hs],     sA1 = srcs[jb + 2 + hs];
    int sA2 = srcs[jb + 4 + hs], sA3 = srcs[jb + 6 + hs];
    for (int j = jb; j < je; j += 8) {
        int s0 = sA0, s1 = sA1, s2 = sA2, s3 = sA3;
        int jn = j + 8;
        if (jn < je) {           // wave-uniform branch
            sA0 = srcs[jn + hs];     sA1 = srcs[jn + 2 + hs];
            sA2 = srcs[jn + 4 + hs]; sA3 = srcs[jn + 6 + hs];
        }
        float e0 = alsrc[s0 * 8 + hh] + adst;
        float e1 = alsrc[s1 * 8 + hh] + adst;
        float e2 = alsrc[s2 * 8 + hh] + adst;
        float e3 = alsrc[s3 * 8 + hh] + adst;
        unsigned q0 = *(const unsigned short*)(h1 + (size_t)s0 * 64 + 2 * cp);
        unsigned q1 = *(const unsigned short*)(h1 + (size_t)s1 * 64 + 2 * cp);
        unsigned q2 = *(const unsigned short*)(h1 + (size_t)s2 * 64 + 2 * cp);
        unsigned q3 = *(const unsigned short*)(h1 + (size_t)s3 * 64 + 2 * cp);
        float p0 = __expf(fmaxf(e0, 0.2f * e0));
        float p1 = __expf(fmaxf(e1, 0.2f * e1));
        float p2 = __expf(fmaxf(e2, 0.2f * e2));
        float p3 = __expf(fmaxf(e3, 0.2f * e3));
        float2 f0 = fp8pair_to_f32(q0), f1 = fp8pair_to_f32(q1);
        float2 f2 = fp8pair_to_f32(q2), f3 = fp8pair_to_f32(q3);
        ssum += (p0 + p1) + (p2 + p3);
        ax += p0 * f0.x + p1 * f1.x + p2 * f2.x + p3 * f3.x;
        ay += p0 * f0.y + p1 * f1.y + p2 * f2.y + p3 * f3.y;
    }
    ssum += __shfl_xor(ssum, 32, 64);
    ax += __shfl_xor(ax, 32, 64);
    ay += __shfl_xor(ay, 32, 64);
    if (hs == 0) {
        float2 bv = *(const float2*)(b1 + 2 * cp);
        float inv = 1.f / ssum;
        float vx = ax * inv + bv.x;
        float vy = ay * inv + bv.y;
        vx = (vx > 0.f) ? vx : (__expf(vx) - 1.f);   // ELU
        vy = (vy > 0.f) ? vy : (__expf(vy) - 1.f);
        *(__half2*)(hout + (size_t)d * 64 + 2 * cp) = __floats2half2_rn(vx, vy);
    }
}

// ---------------- layer 2 node GEMM via MFMA (h2 fp16, 40 cols in 3 ctiles) -----
__global__ __launch_bounds__(256) void k_gemm2(
    const __half* __restrict__ hout, const _Float16* __restrict__ Bf2,
    const float* __restrict__ a_src2, const float* __restrict__ a_dst2,
    __half* __restrict__ h2, float* __restrict__ al2s, float* __restrict__ al2d) {
    int wave = threadIdx.x >> 6, lane = threadIdx.x & 63;
    int row0 = blockIdx.x * 64 + wave * 16;
    if (row0 >= NN) return;
    int g = lane >> 4, li = lane & 15;
    int myrow = row0 + li;
    half8 B[6];
    const half8* bp = (const half8*)Bf2;
    #pragma unroll
    for (int i = 0; i < 6; i++) B[i] = bp[i * 64 + lane];
    floatx4 acc[3] = {{0,0,0,0},{0,0,0,0},{0,0,0,0}};
    #pragma unroll
    for (int kk = 0; kk < 2; kk++) {
        int k0 = kk * 32 + g * 8;
        half8 av = *(const half8*)(hout + (size_t)myrow * 64 + k0);
        #pragma unroll
        for (int ct = 0; ct < 3; ct++)
            acc[ct] = __builtin_amdgcn_mfma_f32_16x16x32_f16(av, B[kk * 3 + ct], acc[ct], 0, 0, 0);
    }
    float ts[4] = {0.f, 0.f, 0.f, 0.f}, td[4] = {0.f, 0.f, 0.f, 0.f};
    #pragma unroll
    for (int ct = 0; ct < 3; ct++) {
        int col = ct * 16 + li;
        bool ok = (col < 40);
        float asv = ok ? a_src2[col] : 0.f;
        float adv = ok ? a_dst2[col] : 0.f;
        #pragma unroll
        for (int r = 0; r < 4; r++) {
            ts[r] += acc[ct][r] * asv;
            td[r] += acc[ct][r] * adv;
            if (ok) h2[(size_t)(row0 + 4 * g + r) * 40 + col] = __float2half(acc[ct][r]);
        }
    }
    #pragma unroll
    for (int off = 1; off <= 8; off <<= 1)
        #pragma unroll
        for (int r = 0; r < 4; r++) {
            ts[r] += __shfl_xor(ts[r], off, 64);
            td[r] += __shfl_xor(td[r], off, 64);
        }
    if (li == 0) {
        #pragma unroll
        for (int r = 0; r < 4; r++) {
            int row = row0 + 4 * g + r;
            al2s[row] = ts[r];
            al2d[row] = td[r];
        }
    }
}

// ------- layer 2 aggregation + fused log_softmax; padded segments, prefetch -----
__global__ __launch_bounds__(256) void k_agg2(
    const int2* __restrict__ rowseg, const int* __restrict__ srcs,
    const float* __restrict__ al2s, const float* __restrict__ al2d,
    const __half* __restrict__ h2, const float* __restrict__ b2,
    float* __restrict__ out) {
    int wave = threadIdx.x >> 6;
    int lane = threadIdx.x & 63;
    int d = blockIdx.x * 4 + wave;
    if (d >= NN) return;
    int hs = lane >> 5;
    int cp = lane & 31;              // cols 2cp,2cp+1; valid if cp<20
    bool act = (cp < 20);
    int cpc = act ? cp : 0;
    float adst = al2d[d];
    int2 seg = rowseg[d];
    int jb = seg.x, je = seg.y;
    float ssum = 0.f, ax = 0.f, ay = 0.f;
    int sA0 = srcs[jb + hs],     sA1 = srcs[jb + 2 + hs];
    int sA2 = srcs[jb + 4 + hs], sA3 = srcs[jb + 6 + hs];
    for (int j = jb; j < je; j += 8) {
        int s0 = sA0, s1 = sA1, s2 = sA2, s3 = sA3;
        int jn = j + 8;
        if (jn < je) {
            sA0 = srcs[jn + hs];     sA1 = srcs[jn + 2 + hs];
            sA2 = srcs[jn + 4 + hs]; sA3 = srcs[jn + 6 + hs];
        }
        float e0 = al2s[s0] + adst;
        float e1 = al2s[s1] + adst;
        float e2 = al2s[s2] + adst;
        float e3 = al2s[s3] + adst;
        __half2 v0 = *(const __half2*)(h2 + (size_t)s0 * 40 + 2 * cpc);
        __half2 v1 = *(const __half2*)(h2 + (size_t)s1 * 40 + 2 * cpc);
        __half2 v2 = *(const __half2*)(h2 + (size_t)s2 * 40 + 2 * cpc);
        __half2 v3 = *(const __half2*)(h2 + (size_t)s3 * 40 + 2 * cpc);
        float p0 = __expf(fmaxf(e0, 0.2f * e0));
        float p1 = __expf(fmaxf(e1, 0.2f * e1));
        float p2 = __expf(fmaxf(e2, 0.2f * e2));
        float p3 = __expf(fmaxf(e3, 0.2f * e3));
        float2 f0 = __half22float2(v0), f1 = __half22float2(v1);
        float2 f2 = __half22float2(v2), f3 = __half22float2(v3);
        ssum += (p0 + p1) + (p2 + p3);
        ax += p0 * f0.x + p1 * f1.x + p2 * f2.x + p3 * f3.x;
        ay += p0 * f0.y + p1 * f1.y + p2 * f2.y + p3 * f3.y;
    }
    ssum += __shfl_xor(ssum, 32, 64);
    ax += __shfl_xor(ax, 32, 64);
    ay += __shfl_xor(ay, 32, 64);
    float inv = 1.f / ssum;
    float2 bv = *(const float2*)(b2 + 2 * cpc);
    float ox = ax * inv + bv.x;
    float oy = ay * inv + bv.y;
    float mo = act ? fmaxf(ox, oy) : -3.0e38f;
    #pragma unroll
    for (int off = 16; off; off >>= 1) mo = fmaxf(mo, __shfl_xor(mo, off, 64));
    float te = act ? (__expf(ox - mo) + __expf(oy - mo)) : 0.f;
    #pragma unroll
    for (int off = 16; off; off >>= 1) te += __shfl_xor(te, off, 64);
    float ls = __logf(te);
    if (act && hs == 0)
        *(float2*)(out + (size_t)d * 40 + 2 * cp) = make_float2(ox - mo - ls, oy - mo - ls);
}

extern "C" void kernel_launch(void* const* d_in, const int* in_sizes, int n_in,
                              void* d_out, int out_size, void* d_ws, size_t ws_size,
                              hipStream_t stream) {
    (void)in_sizes; (void)n_in; (void)out_size; (void)ws_size;
    const float* x    = (const float*)d_in[0];
    const float* topo = (const float*)d_in[1];
    const int*   ei   = (const int*)d_in[2];
    const float* W1   = (const float*)d_in[3];
    const float* as1  = (const float*)d_in[4];
    const float* ad1  = (const float*)d_in[5];
    const float* b1   = (const float*)d_in[6];
    const float* W2   = (const float*)d_in[7];
    const float* as2  = (const float*)d_in[8];
    const float* ad2  = (const float*)d_in[9];
    const float* b2   = (const float*)d_in[10];
    float* out = (float*)d_out;

    char* ws = (char*)d_ws;
    size_t off = 0;
    auto alloc = [&](size_t bytes) {
        void* p = ws + off;
        off += (bytes + 255) / 256 * 256;
        return p;
    };
    int2*          rowseg     = (int2*)alloc((size_t)NN * 8);
    int*           cursor     = (int*)alloc(NBUCK * 4);
    unsigned*      bucketData = (unsigned*)alloc((size_t)NBUCK * CAP * 4);
    int*           srcs       = (int*)alloc((size_t)SRCS_MAX * 4);
    float*         alsrc1     = (float*)alloc((size_t)(NN + 1) * 8 * 4);
    float*         aldst1     = (float*)alloc((size_t)NN * 8 * 4);
    float*         al2s       = (float*)alloc((NN + 1) * 4);
    float*         al2d       = (float*)alloc(NN * 4);
    _Float16*      Bf1        = (_Float16*)alloc(4 * 4 * 64 * 8 * 2);
    _Float16*      Bf2        = (_Float16*)alloc(2 * 3 * 64 * 8 * 2);
    unsigned char* h1         = (unsigned char*)alloc((size_t)(NN + 1) * 64);
    __half*        hout       = (__half*)alloc((size_t)NN * 64 * 2);
    __half*        h2         = (__half*)alloc((size_t)(NN + 1) * 40 * 2);

    k_prep    <<<7,         256,  0, stream>>>(W1, W2, Bf1, Bf2, cursor, alsrc1, al2s);
    k_fusedAG <<<NBA + NGB, 256,  0, stream>>>(ei, cursor, bucketData,
                                               x, topo, Bf1, as1, ad1, h1, alsrc1, aldst1);
    k_bucketB <<<NBUCK,     1024, 0, stream>>>(bucketData, cursor, rowseg, srcs);
    k_agg1    <<<(NN + 3) / 4, 256, 0, stream>>>(rowseg, srcs, alsrc1, aldst1, h1, b1, hout);
    k_gemm2   <<<782,       256,  0, stream>>>(hout, Bf2, as2, ad2, h2, al2s, al2d);
    k_agg2    <<<(NN + 3) / 4, 256, 0, stream>>>(rowseg, srcs, al2s, al2d, h2, b2, out);
}